// Round 5
// baseline (140.769 us; speedup 1.0000x reference)
//
#include <hip/hip_runtime.h>
#include <stdint.h>

#define NV 8192   // vision rows
#define MT 8192   // text rows
#define DD 128    // feature dim
#define KB 768    // BERT dim

typedef __attribute__((ext_vector_type(8))) short short8;
typedef __attribute__((ext_vector_type(4))) float f32x4;

__device__ __forceinline__ ushort f2bf(float f) {
  uint32_t u = __float_as_uint(f);
  u += 0x7FFF + ((u >> 16) & 1);   // round-to-nearest-even
  return (ushort)(u >> 16);
}

// ---------------- Kernel 1: vision row-normalize -> bf16 ----------------
__global__ __launch_bounds__(256) void k_visnorm(const float* __restrict__ vis,
                                                 ushort* __restrict__ vn) {
  const int tx = threadIdx.x & 15;
  const int r  = blockIdx.x * 16 + (threadIdx.x >> 4);
  const float* p = vis + (size_t)r * DD + tx * 8;
  float4 a = *(const float4*)p;
  float4 b = *(const float4*)(p + 4);
  float s = a.x*a.x + a.y*a.y + a.z*a.z + a.w*a.w
          + b.x*b.x + b.y*b.y + b.z*b.z + b.w*b.w;
  s += __shfl_xor(s, 1, 16);
  s += __shfl_xor(s, 2, 16);
  s += __shfl_xor(s, 4, 16);
  s += __shfl_xor(s, 8, 16);
  const float inv = 1.0f / fmaxf(sqrtf(s), 1e-8f);
  union { ushort u[8]; uint4 v; } o;
  o.u[0] = f2bf(a.x * inv); o.u[1] = f2bf(a.y * inv);
  o.u[2] = f2bf(a.z * inv); o.u[3] = f2bf(a.w * inv);
  o.u[4] = f2bf(b.x * inv); o.u[5] = f2bf(b.y * inv);
  o.u[6] = f2bf(b.z * inv); o.u[7] = f2bf(b.w * inv);
  *(uint4*)(vn + (size_t)r * DD + tx * 8) = o.v;
}

// ---------------- Kernel 2: f32 -> bf16 bulk convert (w only) ------------
__global__ __launch_bounds__(256) void k_cvt(const float* __restrict__ src,
                                             ushort* __restrict__ dst) {
  const size_t i = ((size_t)blockIdx.x * 256 + threadIdx.x) * 8;
  float4 a = *(const float4*)(src + i);
  float4 b = *(const float4*)(src + i + 4);
  union { ushort u[8]; uint4 v; } o;
  o.u[0] = f2bf(a.x); o.u[1] = f2bf(a.y); o.u[2] = f2bf(a.z); o.u[3] = f2bf(a.w);
  o.u[4] = f2bf(b.x); o.u[5] = f2bf(b.y); o.u[6] = f2bf(b.z); o.u[7] = f2bf(b.w);
  *(uint4*)(dst + i) = o.v;
}

// ---------------- Kernel 3: projection MFMA (fused txt cvt) + bias + norm
// 1 wave/block, 512 blocks; wave: 16 text rows x 128 dims.
// A-fragments converted f32->bf16 in-register (txt read once, no tb buffer).
__global__ __launch_bounds__(64) void k_projnorm(const float* __restrict__ txt,
                                                 const ushort* __restrict__ wb,
                                                 const float* __restrict__ bias,
                                                 ushort* __restrict__ tn) {
  const int lane = threadIdx.x;
  const int row0 = blockIdx.x * 16;
  const int lrow = lane & 15;
  const int g    = lane >> 4;        // 0..3
  const int koff = g * 8;

  const float*  ap = txt + (size_t)(row0 + lrow) * KB + koff;
  const ushort* bp = wb + (size_t)lrow * KB + koff;

  f32x4 acc[8] = {};

#pragma unroll 4
  for (int ks = 0; ks < KB / 32; ++ks) {
    float4 f0 = *(const float4*)(ap + ks * 32);
    float4 f1 = *(const float4*)(ap + ks * 32 + 4);
    short8 a;
    a[0] = (short)f2bf(f0.x); a[1] = (short)f2bf(f0.y);
    a[2] = (short)f2bf(f0.z); a[3] = (short)f2bf(f0.w);
    a[4] = (short)f2bf(f1.x); a[5] = (short)f2bf(f1.y);
    a[6] = (short)f2bf(f1.z); a[7] = (short)f2bf(f1.w);
#pragma unroll
    for (int n = 0; n < 8; ++n) {
      short8 b = *(const short8*)(bp + (size_t)n * 16 * KB + ks * 32);
      acc[n] = __builtin_amdgcn_mfma_f32_16x16x32_bf16(a, b, acc[n], 0, 0, 0);
    }
  }

  // D layout: row = g*4 + j, col = n*16 + lrow. bias add:
#pragma unroll
  for (int n = 0; n < 8; ++n) {
    float bv = bias[n * 16 + lrow];
#pragma unroll
    for (int j = 0; j < 4; ++j) acc[n][j] += bv;
  }
  float s0 = 0.f, s1 = 0.f, s2 = 0.f, s3 = 0.f;
#pragma unroll
  for (int n = 0; n < 8; ++n) {
    s0 += acc[n][0] * acc[n][0];
    s1 += acc[n][1] * acc[n][1];
    s2 += acc[n][2] * acc[n][2];
    s3 += acc[n][3] * acc[n][3];
  }
#pragma unroll
  for (int d = 1; d < 16; d <<= 1) {
    s0 += __shfl_xor(s0, d, 16);
    s1 += __shfl_xor(s1, d, 16);
    s2 += __shfl_xor(s2, d, 16);
    s3 += __shfl_xor(s3, d, 16);
  }
  float inv[4];
  inv[0] = 1.0f / fmaxf(sqrtf(s0), 1e-8f);
  inv[1] = 1.0f / fmaxf(sqrtf(s1), 1e-8f);
  inv[2] = 1.0f / fmaxf(sqrtf(s2), 1e-8f);
  inv[3] = 1.0f / fmaxf(sqrtf(s3), 1e-8f);

#pragma unroll
  for (int n = 0; n < 8; ++n)
#pragma unroll
    for (int j = 0; j < 4; ++j)
      tn[(size_t)(row0 + g * 4 + j) * DD + n * 16 + lrow] = f2bf(acc[n][j] * inv[j]);
}

// ---------------- Kernel 4: similarity GEMM, 256x256 tiles, nt stores ----
// 1024 blocks (XCD-swizzled), 512 thr = 8 waves (4 M-quadrants x 2 N-halves).
// Wave = 64x128 output, acc[4][8]. Fragments direct from global (L2-hot;
// nt output stores keep vn/tn from being evicted). Epilogue: two 128-row
// half-passes through a 128KB LDS transpose -> coalesced 1KB/wave nt stores.
__global__ __launch_bounds__(512, 2) void k_sim(const ushort* __restrict__ vn,
                                                const ushort* __restrict__ tn,
                                                float* __restrict__ out) {
  __shared__ float lsf[128 * 256];   // 128 KB

  // XCD swizzle: 1024 blocks, 8 XCDs, 128 consecutive tiles per XCD
  const int lin  = blockIdx.x;
  const int nlin = (lin & 7) * 128 + (lin >> 3);
  const int by   = nlin >> 5;        // 0..31
  const int bx   = nlin & 31;
  const int row0 = by * 256;
  const int col0 = bx * 256;

  const int t    = threadIdx.x;
  const int lane = t & 63;
  const int wave = t >> 6;
  const int wr   = wave >> 1;        // 0..3  (64-row quadrant)
  const int wc   = wave & 1;         // 0..1  (128-col half)
  const int lrow = lane & 15;
  const int kgrp = lane >> 4;        // 0..3

  const ushort* ap = vn + (size_t)(row0 + wr * 64 + lrow) * DD + kgrp * 8;
  const ushort* bp = tn + (size_t)(col0 + wc * 128 + lrow) * DD + kgrp * 8;

  f32x4 acc[4][8] = {};

#pragma unroll
  for (int ks = 0; ks < 4; ++ks) {
    short8 a[4], b[8];
#pragma unroll
    for (int m = 0; m < 4; ++m)
      a[m] = *(const short8*)(ap + (size_t)m * 16 * DD + ks * 32);
#pragma unroll
    for (int n = 0; n < 8; ++n)
      b[n] = *(const short8*)(bp + (size_t)n * 16 * DD + ks * 32);
#pragma unroll
    for (int m = 0; m < 4; ++m)
#pragma unroll
      for (int n = 0; n < 8; ++n)
        acc[m][n] = __builtin_amdgcn_mfma_f32_16x16x32_bf16(a[m], b[n], acc[m][n], 0, 0, 0);
  }

  // Epilogue: half h covers tile rows [h*128, h*128+128) (waves wr>>1 == h).
#pragma unroll
  for (int h = 0; h < 2; ++h) {
    __syncthreads();
    if ((wr >> 1) == h) {
      const int rbase = (wr & 1) * 64;
#pragma unroll
      for (int m = 0; m < 4; ++m)
#pragma unroll
        for (int n = 0; n < 8; ++n) {
          const int c = wc * 128 + n * 16 + lrow;
#pragma unroll
          for (int j = 0; j < 4; ++j) {
            const int rl = rbase + m * 16 + kgrp * 4 + j;
            lsf[rl * 256 + (c ^ (((rl >> 2) & 1) << 4))] = acc[m][n][j];
          }
        }
    }
    __syncthreads();
    const f32x4* lsf4 = (const f32x4*)lsf;
#pragma unroll
    for (int p = 0; p < 16; ++p) {
      const int fi = p * 512 + t;
      const int rl = fi >> 6;           // 0..127
      const int c4 = fi & 63;
      f32x4 v = lsf4[rl * 64 + (c4 ^ (((rl >> 2) & 1) << 2))];
      __builtin_nontemporal_store(
          v, (f32x4*)(out + (size_t)(row0 + h * 128 + rl) * MT + col0 + c4 * 4));
    }
  }
}

extern "C" void kernel_launch(void* const* d_in, const int* in_sizes, int n_in,
                              void* d_out, int out_size, void* d_ws, size_t ws_size,
                              hipStream_t stream) {
  (void)in_sizes; (void)n_in; (void)out_size; (void)ws_size;
  const float* vis  = (const float*)d_in[0];  // [8192,128]
  const float* txt  = (const float*)d_in[1];  // [8192,768]
  const float* w    = (const float*)d_in[2];  // [128,768]
  const float* bias = (const float*)d_in[3];  // [128]
  float* out = (float*)d_out;                 // [8192,8192]

  // ws layout: vn 2MB @0 | tn 2MB @2MB | wb 192KB @4MB
  char* ws = (char*)d_ws;
  ushort* vn = (ushort*)(ws);
  ushort* tn = (ushort*)(ws + (size_t)2097152);
  ushort* wb = (ushort*)(ws + (size_t)4194304);

  k_visnorm<<<NV / 16, 256, 0, stream>>>(vis, vn);
  k_cvt<<<(DD * KB) / 2048, 256, 0, stream>>>(w, wb);
  k_projnorm<<<MT / 16, 64, 0, stream>>>(txt, wb, bias, tn);
  k_sim<<<1024, 512, 0, stream>>>(vn, tn, out);
}

// Round 6
// 137.531 us; speedup vs baseline: 1.0235x; 1.0235x over previous
//
#include <hip/hip_runtime.h>
#include <stdint.h>

#define NV 8192   // vision rows
#define MT 8192   // text rows
#define DD 128    // feature dim
#define KB 768    // BERT dim

typedef __attribute__((ext_vector_type(8))) short short8;
typedef __attribute__((ext_vector_type(4))) float f32x4;

__device__ __forceinline__ ushort f2bf(float f) {
  uint32_t u = __float_as_uint(f);
  u += 0x7FFF + ((u >> 16) & 1);   // round-to-nearest-even
  return (ushort)(u >> 16);
}

// ---------------- Kernel 1: vision row-normalize -> bf16 ----------------
__global__ __launch_bounds__(256) void k_visnorm(const float* __restrict__ vis,
                                                 ushort* __restrict__ vn) {
  const int tx = threadIdx.x & 15;
  const int r  = blockIdx.x * 16 + (threadIdx.x >> 4);
  const float* p = vis + (size_t)r * DD + tx * 8;
  float4 a = *(const float4*)p;
  float4 b = *(const float4*)(p + 4);
  float s = a.x*a.x + a.y*a.y + a.z*a.z + a.w*a.w
          + b.x*b.x + b.y*b.y + b.z*b.z + b.w*b.w;
  s += __shfl_xor(s, 1, 16);
  s += __shfl_xor(s, 2, 16);
  s += __shfl_xor(s, 4, 16);
  s += __shfl_xor(s, 8, 16);
  const float inv = 1.0f / fmaxf(sqrtf(s), 1e-8f);
  union { ushort u[8]; uint4 v; } o;
  o.u[0] = f2bf(a.x * inv); o.u[1] = f2bf(a.y * inv);
  o.u[2] = f2bf(a.z * inv); o.u[3] = f2bf(a.w * inv);
  o.u[4] = f2bf(b.x * inv); o.u[5] = f2bf(b.y * inv);
  o.u[6] = f2bf(b.z * inv); o.u[7] = f2bf(b.w * inv);
  *(uint4*)(vn + (size_t)r * DD + tx * 8) = o.v;
}

// ---------------- Kernel 2: f32 -> bf16 bulk convert (w only) ------------
__global__ __launch_bounds__(256) void k_cvt(const float* __restrict__ src,
                                             ushort* __restrict__ dst) {
  const size_t i = ((size_t)blockIdx.x * 256 + threadIdx.x) * 8;
  float4 a = *(const float4*)(src + i);
  float4 b = *(const float4*)(src + i + 4);
  union { ushort u[8]; uint4 v; } o;
  o.u[0] = f2bf(a.x); o.u[1] = f2bf(a.y); o.u[2] = f2bf(a.z); o.u[3] = f2bf(a.w);
  o.u[4] = f2bf(b.x); o.u[5] = f2bf(b.y); o.u[6] = f2bf(b.z); o.u[7] = f2bf(b.w);
  *(uint4*)(dst + i) = o.v;
}

// ---------------- Kernel 3: projection MFMA (fused txt cvt) + bias + norm
__global__ __launch_bounds__(64) void k_projnorm(const float* __restrict__ txt,
                                                 const ushort* __restrict__ wb,
                                                 const float* __restrict__ bias,
                                                 ushort* __restrict__ tn) {
  const int lane = threadIdx.x;
  const int row0 = blockIdx.x * 16;
  const int lrow = lane & 15;
  const int g    = lane >> 4;        // 0..3
  const int koff = g * 8;

  const float*  ap = txt + (size_t)(row0 + lrow) * KB + koff;
  const ushort* bp = wb + (size_t)lrow * KB + koff;

  f32x4 acc[8] = {};

#pragma unroll 4
  for (int ks = 0; ks < KB / 32; ++ks) {
    float4 f0 = *(const float4*)(ap + ks * 32);
    float4 f1 = *(const float4*)(ap + ks * 32 + 4);
    short8 a;
    a[0] = (short)f2bf(f0.x); a[1] = (short)f2bf(f0.y);
    a[2] = (short)f2bf(f0.z); a[3] = (short)f2bf(f0.w);
    a[4] = (short)f2bf(f1.x); a[5] = (short)f2bf(f1.y);
    a[6] = (short)f2bf(f1.z); a[7] = (short)f2bf(f1.w);
#pragma unroll
    for (int n = 0; n < 8; ++n) {
      short8 b = *(const short8*)(bp + (size_t)n * 16 * KB + ks * 32);
      acc[n] = __builtin_amdgcn_mfma_f32_16x16x32_bf16(a, b, acc[n], 0, 0, 0);
    }
  }

  // D layout: row = g*4 + j, col = n*16 + lrow. bias:
#pragma unroll
  for (int n = 0; n < 8; ++n) {
    float bv = bias[n * 16 + lrow];
#pragma unroll
    for (int j = 0; j < 4; ++j) acc[n][j] += bv;
  }
  float s0 = 0.f, s1 = 0.f, s2 = 0.f, s3 = 0.f;
#pragma unroll
  for (int n = 0; n < 8; ++n) {
    s0 += acc[n][0] * acc[n][0];
    s1 += acc[n][1] * acc[n][1];
    s2 += acc[n][2] * acc[n][2];
    s3 += acc[n][3] * acc[n][3];
  }
#pragma unroll
  for (int d = 1; d < 16; d <<= 1) {
    s0 += __shfl_xor(s0, d, 16);
    s1 += __shfl_xor(s1, d, 16);
    s2 += __shfl_xor(s2, d, 16);
    s3 += __shfl_xor(s3, d, 16);
  }
  float inv[4];
  inv[0] = 1.0f / fmaxf(sqrtf(s0), 1e-8f);
  inv[1] = 1.0f / fmaxf(sqrtf(s1), 1e-8f);
  inv[2] = 1.0f / fmaxf(sqrtf(s2), 1e-8f);
  inv[3] = 1.0f / fmaxf(sqrtf(s3), 1e-8f);

#pragma unroll
  for (int n = 0; n < 8; ++n)
#pragma unroll
    for (int j = 0; j < 4; ++j)
      tn[(size_t)(row0 + g * 4 + j) * DD + n * 16 + lrow] = f2bf(acc[n][j] * inv[j]);
}

// ---------------- Kernel 4: similarity GEMM (R2 base + XCD swizzle + nt) -
// 4096 blocks, 256 thr = 4 waves (2x2), tile 128x128, K=128.
// Fragments direct from global (vn/tn stay L2-hot because output stores are
// NONTEMPORAL -> no L2 write-allocate flood). Each 16-lane group's scalar
// stores cover one full aligned 64B line.
__global__ __launch_bounds__(256, 3) void k_sim(const ushort* __restrict__ vn,
                                                const ushort* __restrict__ tn,
                                                float* __restrict__ out) {
  // bijective XCD swizzle: 4096 blocks, 8 XCDs, 512 consecutive per XCD
  const int lin  = blockIdx.x;
  const int nlin = (lin & 7) * 512 + (lin >> 3);
  const int by   = nlin >> 6;
  const int bx   = nlin & 63;

  const int lane = threadIdx.x & 63;
  const int wave = threadIdx.x >> 6;
  const int row0 = by * 128 + (wave >> 1) * 64;
  const int col0 = bx * 128 + (wave & 1) * 64;
  const int lrow = lane & 15;
  const int koff = (lane >> 4) * 8;

  const ushort* ap = vn + (size_t)(row0 + lrow) * DD + koff;
  const ushort* bp = tn + (size_t)(col0 + lrow) * DD + koff;

  f32x4 acc[4][4] = {};

#pragma unroll
  for (int ks = 0; ks < 4; ++ks) {
    short8 a[4], b[4];
#pragma unroll
    for (int m = 0; m < 4; ++m)
      a[m] = *(const short8*)(ap + (size_t)m * 16 * DD + ks * 32);
#pragma unroll
    for (int n = 0; n < 4; ++n)
      b[n] = *(const short8*)(bp + (size_t)n * 16 * DD + ks * 32);
#pragma unroll
    for (int m = 0; m < 4; ++m)
#pragma unroll
      for (int n = 0; n < 4; ++n)
        acc[m][n] = __builtin_amdgcn_mfma_f32_16x16x32_bf16(a[m], b[n], acc[m][n], 0, 0, 0);
  }

  // D layout: row = (lane>>4)*4 + j, col = lane&15; nontemporal stores.
  const int orow = (lane >> 4) * 4;
  const int ocol = lane & 15;
  float* op = out + (size_t)(row0 + orow) * MT + col0 + ocol;
#pragma unroll
  for (int m = 0; m < 4; ++m)
#pragma unroll
    for (int n = 0; n < 4; ++n)
#pragma unroll
      for (int j = 0; j < 4; ++j)
        __builtin_nontemporal_store(acc[m][n][j],
                                    op + (size_t)(m * 16 + j) * MT + n * 16);
}

extern "C" void kernel_launch(void* const* d_in, const int* in_sizes, int n_in,
                              void* d_out, int out_size, void* d_ws, size_t ws_size,
                              hipStream_t stream) {
  (void)in_sizes; (void)n_in; (void)out_size; (void)ws_size;
  const float* vis  = (const float*)d_in[0];  // [8192,128]
  const float* txt  = (const float*)d_in[1];  // [8192,768]
  const float* w    = (const float*)d_in[2];  // [128,768]
  const float* bias = (const float*)d_in[3];  // [128]
  float* out = (float*)d_out;                 // [8192,8192]

  // ws layout: vn 2MB @0 | tn 2MB @2MB | wb 192KB @4MB
  char* ws = (char*)d_ws;
  ushort* vn = (ushort*)(ws);
  ushort* tn = (ushort*)(ws + (size_t)2097152);
  ushort* wb = (ushort*)(ws + (size_t)4194304);

  k_visnorm<<<NV / 16, 256, 0, stream>>>(vis, vn);
  k_cvt<<<(DD * KB) / 2048, 256, 0, stream>>>(w, wb);
  k_projnorm<<<MT / 16, 64, 0, stream>>>(txt, wb, bias, tn);
  k_sim<<<4096, 256, 0, stream>>>(vn, tn, out);
}